// Round 9
// baseline (399.285 us; speedup 1.0000x reference)
//
#include <hip/hip_runtime.h>
#include <hip/hip_fp16.h>
#include <cstdint>
#include <cstddef>

#define N_NODES 50000
#define N_EDGES 1600000
#define NEG_SLOPE 0.2f
#define GAT_EPS 1e-16f

// ---------------- single-block exclusive scan, 4 elems/thread ----------------

__global__ void k_scan(const int* __restrict__ cnt, int* __restrict__ row_start) {
    __shared__ int wsum[16];
    __shared__ int wpre[16];
    __shared__ int total;
    __shared__ int chunk_base;
    int t = threadIdx.x;
    int lane = t & 63, wid = t >> 6;
    if (t == 0) chunk_base = 0;
    __syncthreads();
    for (int base = 0; base < N_NODES; base += 4096) {
        int i0 = base + t * 4;
        int v0 = (i0 + 0 < N_NODES) ? cnt[i0 + 0] : 0;
        int v1 = (i0 + 1 < N_NODES) ? cnt[i0 + 1] : 0;
        int v2 = (i0 + 2 < N_NODES) ? cnt[i0 + 2] : 0;
        int v3 = (i0 + 3 < N_NODES) ? cnt[i0 + 3] : 0;
        int s0 = v0, s1 = s0 + v1, s2 = s1 + v2, s3 = s2 + v3;
        int x = s3;
#pragma unroll
        for (int off = 1; off < 64; off <<= 1) {
            int y = __shfl_up(x, off, 64);
            if (lane >= off) x += y;
        }
        if (lane == 63) wsum[wid] = x;
        __syncthreads();
        if (t < 16) {
            int w = wsum[t];
            int xx = w;
#pragma unroll
            for (int off = 1; off < 16; off <<= 1) {
                int y = __shfl_up(xx, off, 16);
                if (t >= off) xx += y;
            }
            wpre[t] = xx - w;
            if (t == 15) total = xx;
        }
        __syncthreads();
        int excl = chunk_base + wpre[wid] + (x - s3);
        if (i0 + 3 < N_NODES) {
            ((int4*)row_start)[i0 >> 2] = make_int4(excl, excl + s0, excl + s1, excl + s2);
        } else {
            if (i0 + 0 < N_NODES) row_start[i0 + 0] = excl;
            if (i0 + 1 < N_NODES) row_start[i0 + 1] = excl + s0;
            if (i0 + 2 < N_NODES) row_start[i0 + 2] = excl + s1;
        }
        __syncthreads();
        if (t == 0) chunk_base += total;
        __syncthreads();
    }
    if (t == 0) row_start[N_NODES] = chunk_base;
}

// scatter + layer-1 edge weights, packed {src,w0,w1,pad} 16B entry.
// Dst-bucketed pass confines the dirty write region (L2 keeps lines until full).
__global__ void k_scatter_w(const int* __restrict__ ei, const int* __restrict__ row_start,
                            int* __restrict__ fill, int4* __restrict__ csr,
                            const float* __restrict__ a_src1, const float* __restrict__ a_dst1,
                            int lo, int hi) {
    int i = blockIdx.x * blockDim.x + threadIdx.x;
    if (i >= N_EDGES) return;
    int d = ei[N_EDGES + i];
    if (d < lo || d >= hi) return;
    int s = ei[i];
    int pos = atomicAdd(&fill[d], 1);
    int slot = row_start[d] + pos;
    float2 as = ((const float2*)a_src1)[s];
    float2 ad = ((const float2*)a_dst1)[d];
    float e0 = as.x + ad.x; e0 = (e0 >= 0.f) ? e0 : NEG_SLOPE * e0;
    float e1 = as.y + ad.y; e1 = (e1 >= 0.f) ? e1 : NEG_SLOPE * e1;
    csr[slot] = make_int4(s, __float_as_int(expf(e0)), __float_as_int(expf(e1)), 0);
}

// ---------------- Layer 1 GEMM (fp16 out) + attention scalars + fused edge count ----------------
// x tile in LDS (16 KB only -> high occupancy); W1 fragments read from L2
// (64 KB chip-hot, fully coalesced 512 B/wave loads). 4x4 register tile.

__global__ __launch_bounds__(256) void k_gemm1c(
    const float* __restrict__ x, const float* __restrict__ W1,
    const float* __restrict__ att_src, const float* __restrict__ att_dst,
    __half* __restrict__ h1, float* __restrict__ a_src, float* __restrict__ a_dst,
    const int* __restrict__ ei, int* __restrict__ cnt) {
    __shared__ float xl[32 * 128];     // 16 KB
    int t = threadIdx.x;
    int node0 = blockIdx.x * 32;
    // fused edge counting FIRST: fire-and-forget atomics overlap staging + compute
    {
        int e0 = blockIdx.x * 1024;
        int e1 = e0 + 1024; if (e1 > N_EDGES) e1 = N_EDGES;
        for (int e = e0 + t; e < e1; e += 256)
            atomicAdd(&cnt[ei[N_EDGES + e]], 1);
    }
    {
        float4* xlv = (float4*)xl;
        for (int j = t; j < 32 * 128 / 4; j += 256) {
            int n = j >> 5;
            int rem = j & 31;
            int gn = node0 + n;
            float4 v = make_float4(0.f, 0.f, 0.f, 0.f);
            if (gn < N_NODES) v = ((const float4*)x)[(size_t)gn * 32 + rem];
            xlv[j] = v;
        }
    }
    __syncthreads();
    int c4 = t & 31;           // float4-channel index (channels 4*c4 .. 4*c4+3)
    int n0 = (t >> 5) * 4;     // 4 block-local nodes
    const float4* W1v = (const float4*)W1;
    float4 acc[4];
#pragma unroll
    for (int i = 0; i < 4; ++i) acc[i] = make_float4(0.f, 0.f, 0.f, 0.f);
#pragma unroll 2
    for (int k0 = 0; k0 < 128; k0 += 4) {
        float4 wr[4], xr[4];
#pragma unroll
        for (int j = 0; j < 4; ++j) wr[j] = W1v[(k0 + j) * 32 + c4];
#pragma unroll
        for (int i = 0; i < 4; ++i) xr[i] = *(const float4*)(xl + (n0 + i) * 128 + k0);
#pragma unroll
        for (int i = 0; i < 4; ++i) {
#pragma unroll
            for (int j = 0; j < 4; ++j) {
                float s = (j == 0) ? xr[i].x : (j == 1) ? xr[i].y : (j == 2) ? xr[i].z : xr[i].w;
                acc[i].x += s * wr[j].x;
                acc[i].y += s * wr[j].y;
                acc[i].z += s * wr[j].z;
                acc[i].w += s * wr[j].w;
            }
        }
    }
    // epilogue: h1 (fp16) + per-(node,head) attention scalars
    int c0 = c4 * 4;
    float4 asv = ((const float4*)att_src)[c4];
    float4 adv = ((const float4*)att_dst)[c4];
    int lane = t & 63;
    int head = (c0 >= 64) ? 1 : 0;
#pragma unroll
    for (int i = 0; i < 4; ++i) {
        int gn = node0 + n0 + i;
        float4 h = acc[i];
        float ps = h.x * asv.x + h.y * asv.y + h.z * asv.z + h.w * asv.w;
        float pd = h.x * adv.x + h.y * adv.y + h.z * adv.z + h.w * adv.w;
#pragma unroll
        for (int off = 8; off >= 1; off >>= 1) {
            ps += __shfl_xor(ps, off, 64);
            pd += __shfl_xor(pd, off, 64);
        }
        if (gn < N_NODES) {
            __half2 p0 = __floats2half2_rn(h.x, h.y);
            __half2 p1 = __floats2half2_rn(h.z, h.w);
            uint2 packed = make_uint2(*(unsigned*)&p0, *(unsigned*)&p1);
            *(uint2*)(h1 + (size_t)gn * 128 + c0) = packed;
            if ((lane & 15) == 0) {
                a_src[gn * 2 + head] = ps;
                a_dst[gn * 2 + head] = pd;
            }
        }
    }
}

// ---------------- Layer 1 aggregation + ELU + fused layer-2 GEMM ----------------
// One wave per destination node, pair-scheme: lanes 0..31 process even edges,
// lanes 32..63 odd edges; each lane covers 4 channels (c0 = 4*(lane&31)).

__global__ __launch_bounds__(256) void k_agg1f(
    const int* __restrict__ row_start, const int4* __restrict__ csr,
    const __half* __restrict__ h1, const float* __restrict__ b1,
    const float* __restrict__ W2,
    const float* __restrict__ att_src2, const float* __restrict__ att_dst2,
    float* __restrict__ h2, float* __restrict__ as2, float* __restrict__ ad2) {
    __shared__ float w2t[16 * 132];     // W2^T, row padded to 132
    __shared__ float rows[4][128];
    int t = threadIdx.x;
    for (int i = t; i < 2048; i += 256) {
        int k = i >> 4, j = i & 15;
        w2t[j * 132 + k] = W2[i];
    }
    __syncthreads();   // only barrier: staging done before any wave needs w2t
    int wv = t >> 6, lane = t & 63;
    int d = blockIdx.x * 4 + wv;
    int row = row_start[d], end = row_start[d + 1];
    int half = lane >> 5;      // 0: even edges, 1: odd edges
    int L = lane & 31;
    int c0 = L * 4;            // 4 channels
    int head = (L >= 16) ? 1 : 0;
    float den = 0.f;
    float4 acc = make_float4(0.f, 0.f, 0.f, 0.f);
    int i = row;
    for (; i + 8 <= end; i += 8) {
#pragma unroll
        for (int p = 0; p < 4; ++p) {
            int idx = i + 2 * p + half;
            int4 e4 = csr[idx];
            int s = e4.x;
            float we = head ? __int_as_float(e4.z) : __int_as_float(e4.y);
            uint2 u = *(const uint2*)(h1 + (size_t)s * 128 + c0);
            __half2 p0 = *(__half2*)&u.x;
            __half2 p1 = *(__half2*)&u.y;
            float2 f0 = __half22float2(p0);
            float2 f1 = __half22float2(p1);
            den += we;
            acc.x += we * f0.x; acc.y += we * f0.y;
            acc.z += we * f1.x; acc.w += we * f1.y;
        }
    }
    for (; i < end; i += 2) {
        int idx = i + half;
        bool ok = idx < end;
        int idxc = ok ? idx : i;
        int4 e4 = csr[idxc];
        int s = e4.x;
        float we = head ? __int_as_float(e4.z) : __int_as_float(e4.y);
        if (!ok) we = 0.f;
        uint2 u = *(const uint2*)(h1 + (size_t)s * 128 + c0);
        __half2 p0 = *(__half2*)&u.x;
        __half2 p1 = *(__half2*)&u.y;
        float2 f0 = __half22float2(p0);
        float2 f1 = __half22float2(p1);
        den += we;
        acc.x += we * f0.x; acc.y += we * f0.y;
        acc.z += we * f1.x; acc.w += we * f1.y;
    }
    // combine even/odd halves (partner lane has same channels & head)
    den += __shfl_xor(den, 32, 64);
    acc.x += __shfl_xor(acc.x, 32, 64);
    acc.y += __shfl_xor(acc.y, 32, 64);
    acc.z += __shfl_xor(acc.z, 32, 64);
    acc.w += __shfl_xor(acc.w, 32, 64);
    float inv = 1.f / (den + GAT_EPS);
    float4 bv = ((const float4*)b1)[L];
    float o0 = acc.x * inv + bv.x;
    float o1 = acc.y * inv + bv.y;
    float o2 = acc.z * inv + bv.z;
    float o3 = acc.w * inv + bv.w;
    o0 = (o0 > 0.f) ? o0 : expm1f(o0);   // ELU
    o1 = (o1 > 0.f) ? o1 : expm1f(o1);
    o2 = (o2 > 0.f) ? o2 : expm1f(o2);
    o3 = (o3 > 0.f) ? o3 : expm1f(o3);
    if (half == 0) *(float4*)(&rows[wv][c0]) = make_float4(o0, o1, o2, o3);
    // rows[wv] written & read by the same wave — no barrier needed
    int j = lane & 15, q = lane >> 4;
    const float* r = rows[wv];
    const float* wt = &w2t[j * 132];
    int k0 = q * 32;
    float acc2 = 0.f;
#pragma unroll
    for (int kk = 0; kk < 32; kk += 4) {
        float4 rv = *(const float4*)(r + k0 + kk);
        float4 w4 = *(const float4*)(wt + k0 + kk);
        acc2 += rv.x * w4.x + rv.y * w4.y + rv.z * w4.z + rv.w * w4.w;
    }
    acc2 += __shfl_xor(acc2, 16, 64);
    acc2 += __shfl_xor(acc2, 32, 64);
    if (lane < 16) {
        h2[(size_t)d * 16 + j] = acc2;
        float ps = acc2 * att_src2[j];
        float pd = acc2 * att_dst2[j];
#pragma unroll
        for (int off = 8; off >= 1; off >>= 1) {
            ps += __shfl_xor(ps, off, 64);
            pd += __shfl_xor(pd, off, 64);
        }
        if (lane == 0) { as2[d] = ps; ad2[d] = pd; }
    }
}

// ---------------- Layer 2 aggregation + bias + softmax: one wave per node ----------------

__global__ __launch_bounds__(256) void k_agg2(
    const int* __restrict__ row_start, const int4* __restrict__ csr,
    const float* __restrict__ h2, const float* __restrict__ as2,
    const float* __restrict__ ad2, const float* __restrict__ b2,
    float* __restrict__ out) {
    int t = threadIdx.x;
    int wv = t >> 6, lane = t & 63;
    int d = blockIdx.x * 4 + wv;
    int row = row_start[d], end = row_start[d + 1];
    float ad = ad2[d];
    int c = lane & 15, q = lane >> 4;
    float den = 0.f, acc = 0.f;
    for (int base = row; base < end; base += 64) {
        int idx = base + lane;
        float w = 0.f; int s = 0;
        if (idx < end) {
            s = csr[idx].x;
            float e = as2[s] + ad;
            e = (e >= 0.f) ? e : NEG_SLOPE * e;
            w = expf(e);
        }
        den += w;
        int m = end - base; if (m > 64) m = 64;
        for (int jj = 0; jj < m; jj += 4) {
            float wj = __shfl(w, jj + q, 64);
            int sj = __shfl(s, jj + q, 64);
            acc += wj * h2[(size_t)sj * 16 + c];
        }
    }
#pragma unroll
    for (int off = 32; off >= 1; off >>= 1) den += __shfl_xor(den, off, 64);
    acc += __shfl_xor(acc, 16, 64);
    acc += __shfl_xor(acc, 32, 64);
    float v = acc / (den + GAT_EPS) + b2[c];
    float mmax = v;
#pragma unroll
    for (int off = 8; off >= 1; off >>= 1) mmax = fmaxf(mmax, __shfl_xor(mmax, off, 16));
    float ex = expf(v - mmax);
    float sum = ex;
#pragma unroll
    for (int off = 8; off >= 1; off >>= 1) sum += __shfl_xor(sum, off, 16);
    if (lane < 16) out[(size_t)d * 16 + c] = ex / sum;
}

// ---------------- launch ----------------

extern "C" void kernel_launch(void* const* d_in, const int* in_sizes, int n_in,
                              void* d_out, int out_size, void* d_ws, size_t ws_size,
                              hipStream_t stream) {
    const float* x        = (const float*)d_in[0];
    const float* W1       = (const float*)d_in[1];
    const float* att_src1 = (const float*)d_in[2];
    const float* att_dst1 = (const float*)d_in[3];
    const float* b1       = (const float*)d_in[4];
    const float* W2       = (const float*)d_in[5];
    const float* att_src2 = (const float*)d_in[6];
    const float* att_dst2 = (const float*)d_in[7];
    const float* b2       = (const float*)d_in[8];
    const int*   ei       = (const int*)d_in[9];   // [2, E]: src row then dst row

    char* p = (char*)d_ws;
    auto alloc = [&](size_t bytes) {
        char* r = p;
        p += (bytes + 255) & ~(size_t)255;
        return r;
    };
    __half* h1     = (__half*)alloc(sizeof(__half) * (size_t)N_NODES * 128);
    float* h2      = (float*)alloc(sizeof(float) * (size_t)N_NODES * 16);
    float* a_src   = (float*)alloc(sizeof(float) * N_NODES * 2);
    float* a_dst   = (float*)alloc(sizeof(float) * N_NODES * 2);
    float* as2     = (float*)alloc(sizeof(float) * N_NODES);
    float* ad2     = (float*)alloc(sizeof(float) * N_NODES);
    int* cnt       = (int*)alloc(sizeof(int) * N_NODES * 2);  // cnt | fill, one memset
    int* fill      = cnt + N_NODES;
    int* row_start = (int*)alloc(sizeof(int) * (N_NODES + 1));
    int4* csr      = (int4*)alloc(sizeof(int4) * (size_t)N_EDGES);

    (void)hipMemsetAsync(cnt, 0, sizeof(int) * N_NODES * 2, stream);
    k_gemm1c<<<(N_NODES + 31) / 32, 256, 0, stream>>>(x, W1, att_src1, att_dst1, h1, a_src, a_dst, ei, cnt);
    k_scan<<<1, 1024, 0, stream>>>(cnt, row_start);
    k_scatter_w<<<(N_EDGES + 255) / 256, 256, 0, stream>>>(ei, row_start, fill, csr, a_src, a_dst, 0, 25000);
    k_scatter_w<<<(N_EDGES + 255) / 256, 256, 0, stream>>>(ei, row_start, fill, csr, a_src, a_dst, 25000, 50000);
    k_agg1f<<<N_NODES / 4, 256, 0, stream>>>(row_start, csr, h1, b1, W2, att_src2, att_dst2, h2, as2, ad2);
    k_agg2<<<N_NODES / 4, 256, 0, stream>>>(row_start, csr, h2, as2, ad2, b2, (float*)d_out);
}

// Round 10
// 380.610 us; speedup vs baseline: 1.0491x; 1.0491x over previous
//
#include <hip/hip_runtime.h>
#include <hip/hip_fp16.h>
#include <cstdint>
#include <cstddef>

#define N_NODES 50000
#define N_EDGES 1600000
#define NEG_SLOPE 0.2f
#define GAT_EPS 1e-16f

typedef _Float16 half8v __attribute__((ext_vector_type(8)));
typedef _Float16 half4v __attribute__((ext_vector_type(4)));
typedef float f32x4 __attribute__((ext_vector_type(4)));

// Channel permutation for h1 storage (MFMA C-reg native order):
// real c = ct*16 + m  <->  cperm = m*8 + ct   (ct=c/16, m=c%16)

// ---------------- prep: x->fp16, W1^T fp16, W2^T/b1 permuted, edge count ----------------

__global__ __launch_bounds__(256) void k_prep(
    const float* __restrict__ x, const float* __restrict__ W1,
    const float* __restrict__ W2, const float* __restrict__ b1,
    const int* __restrict__ ei,
    _Float16* __restrict__ x16, _Float16* __restrict__ w1t,
    float* __restrict__ w2tp, float* __restrict__ b1p,
    int* __restrict__ cnt) {
    int t = threadIdx.x;
    int b = blockIdx.x;
    int gid = b * 256 + t;
    // x convert (rows >= N zero-padded to 50048)
    size_t base = (size_t)gid * 4;
    if (base < (size_t)50048 * 128) {
        float4 v = make_float4(0.f, 0.f, 0.f, 0.f);
        if (base < (size_t)N_NODES * 128) v = *(const float4*)(x + base);
        half4v hv;
        hv[0] = (_Float16)v.x; hv[1] = (_Float16)v.y;
        hv[2] = (_Float16)v.z; hv[3] = (_Float16)v.w;
        *(half4v*)(x16 + base) = hv;
    }
    // edge counting
    if (gid < N_EDGES) atomicAdd(&cnt[ei[N_EDGES + gid]], 1);
    // W1^T fp16, padded rows [128][136]: w1t[c][k] = W1[k][c]
    if (b < 64) {
        int c = b * 2 + (t >> 7), k = t & 127;
        w1t[c * 136 + k] = (_Float16)W1[k * 128 + c];
    } else if (b < 72) {
        int idx = (b - 64) * 256 + t;
        int j = idx >> 7, kp = idx & 127;
        int real = (kp & 7) * 16 + (kp >> 3);
        w2tp[j * 136 + kp] = W2[real * 16 + j];
    } else if (b == 72 && t < 128) {
        int real = (t & 7) * 16 + (t >> 3);
        b1p[t] = b1[real];
    }
}

// ---------------- single-block exclusive scan, 4 elems/thread ----------------

__global__ void k_scan(const int* __restrict__ cnt, int* __restrict__ row_start) {
    __shared__ int wsum[16];
    __shared__ int wpre[16];
    __shared__ int total;
    __shared__ int chunk_base;
    int t = threadIdx.x;
    int lane = t & 63, wid = t >> 6;
    if (t == 0) chunk_base = 0;
    __syncthreads();
    for (int base = 0; base < N_NODES; base += 4096) {
        int i0 = base + t * 4;
        int v0 = (i0 + 0 < N_NODES) ? cnt[i0 + 0] : 0;
        int v1 = (i0 + 1 < N_NODES) ? cnt[i0 + 1] : 0;
        int v2 = (i0 + 2 < N_NODES) ? cnt[i0 + 2] : 0;
        int v3 = (i0 + 3 < N_NODES) ? cnt[i0 + 3] : 0;
        int s0 = v0, s1 = s0 + v1, s2 = s1 + v2, s3 = s2 + v3;
        int x = s3;
#pragma unroll
        for (int off = 1; off < 64; off <<= 1) {
            int y = __shfl_up(x, off, 64);
            if (lane >= off) x += y;
        }
        if (lane == 63) wsum[wid] = x;
        __syncthreads();
        if (t < 16) {
            int w = wsum[t];
            int xx = w;
#pragma unroll
            for (int off = 1; off < 16; off <<= 1) {
                int y = __shfl_up(xx, off, 16);
                if (t >= off) xx += y;
            }
            wpre[t] = xx - w;
            if (t == 15) total = xx;
        }
        __syncthreads();
        int excl = chunk_base + wpre[wid] + (x - s3);
        if (i0 + 3 < N_NODES) {
            ((int4*)row_start)[i0 >> 2] = make_int4(excl, excl + s0, excl + s1, excl + s2);
        } else {
            if (i0 + 0 < N_NODES) row_start[i0 + 0] = excl;
            if (i0 + 1 < N_NODES) row_start[i0 + 1] = excl + s0;
            if (i0 + 2 < N_NODES) row_start[i0 + 2] = excl + s1;
        }
        __syncthreads();
        if (t == 0) chunk_base += total;
        __syncthreads();
    }
    if (t == 0) row_start[N_NODES] = chunk_base;
}

// scatter + layer-1 edge weights, packed {src,w0,w1,pad} 16B entry, dst-bucketed.
__global__ void k_scatter_w(const int* __restrict__ ei, const int* __restrict__ row_start,
                            int* __restrict__ fill, int4* __restrict__ csr,
                            const float* __restrict__ a_src1, const float* __restrict__ a_dst1,
                            int lo, int hi) {
    int i = blockIdx.x * blockDim.x + threadIdx.x;
    if (i >= N_EDGES) return;
    int d = ei[N_EDGES + i];
    if (d < lo || d >= hi) return;
    int s = ei[i];
    int pos = atomicAdd(&fill[d], 1);
    int slot = row_start[d] + pos;
    float2 as = ((const float2*)a_src1)[s];
    float2 ad = ((const float2*)a_dst1)[d];
    float e0 = as.x + ad.x; e0 = (e0 >= 0.f) ? e0 : NEG_SLOPE * e0;
    float e1 = as.y + ad.y; e1 = (e1 >= 0.f) ? e1 : NEG_SLOPE * e1;
    csr[slot] = make_int4(s, __float_as_int(expf(e0)), __float_as_int(expf(e1)), 0);
}

// ---------------- Layer 1 GEMM via MFMA f16 ----------------
// Block: 4 waves x 16 nodes = 64 nodes. Wave: 16 nodes x 128 channels.
// A-frags straight from global x16; B-frags (W1^T fp16) from LDS.
// h1 stored in permuted channel layout (coalesced half8 stores).

__global__ __launch_bounds__(256) void k_gemm1m(
    const _Float16* __restrict__ x16, const _Float16* __restrict__ w1t,
    const float* __restrict__ att_src, const float* __restrict__ att_dst,
    _Float16* __restrict__ h1p, float* __restrict__ a_src, float* __restrict__ a_dst) {
    __shared__ _Float16 wl[128 * 136];   // 34816 B
    int t = threadIdx.x;
    {
        const uint4* src = (const uint4*)w1t;
        uint4* dst = (uint4*)wl;
        for (int j = t; j < 2176; j += 256) dst[j] = src[j];
    }
    __syncthreads();
    int wv = t >> 6, lane = t & 63;
    int m = lane & 15, q = lane >> 4;
    int nb = blockIdx.x * 64 + wv * 16;
    f32x4 acc[8];
#pragma unroll
    for (int ct = 0; ct < 8; ++ct) acc[ct] = (f32x4){0.f, 0.f, 0.f, 0.f};
#pragma unroll
    for (int kc = 0; kc < 4; ++kc) {
        half8v a = *(const half8v*)(x16 + (size_t)(nb + m) * 128 + kc * 32 + q * 8);
#pragma unroll
        for (int ct = 0; ct < 8; ++ct) {
            half8v bf = *(const half8v*)(wl + (ct * 16 + m) * 136 + kc * 32 + q * 8);
            acc[ct] = __builtin_amdgcn_mfma_f32_16x16x32_f16(a, bf, acc[ct], 0, 0, 0);
        }
    }
    // epilogue: attention scalars (fp32) + permuted fp16 h1 store
    float att_s[8], att_d[8];
#pragma unroll
    for (int ct = 0; ct < 8; ++ct) {
        att_s[ct] = att_src[ct * 16 + m];
        att_d[ct] = att_dst[ct * 16 + m];
    }
#pragma unroll
    for (int r = 0; r < 4; ++r) {
        int gn = nb + q * 4 + r;
        half8v hv;
        float ps0 = 0.f, ps1 = 0.f, pd0 = 0.f, pd1 = 0.f;
#pragma unroll
        for (int ct = 0; ct < 8; ++ct) {
            float v = acc[ct][r];
            hv[ct] = (_Float16)v;
            if (ct < 4) { ps0 += v * att_s[ct]; pd0 += v * att_d[ct]; }
            else        { ps1 += v * att_s[ct]; pd1 += v * att_d[ct]; }
        }
#pragma unroll
        for (int off = 8; off >= 1; off >>= 1) {
            ps0 += __shfl_xor(ps0, off, 64);
            ps1 += __shfl_xor(ps1, off, 64);
            pd0 += __shfl_xor(pd0, off, 64);
            pd1 += __shfl_xor(pd1, off, 64);
        }
        if (gn < N_NODES) {
            *(half8v*)(h1p + (size_t)gn * 128 + m * 8) = hv;
            if (m == 0) {
                a_src[gn * 2 + 0] = ps0;
                a_src[gn * 2 + 1] = ps1;
                a_dst[gn * 2 + 0] = pd0;
                a_dst[gn * 2 + 1] = pd1;
            }
        }
    }
}

// ---------------- Layer 1 aggregation + ELU + fused layer-2 GEMM ----------------
// One wave per node, pair-scheme: lanes 0..31 even edges, 32..63 odd edges.
// Channels are in PERMUTED space: c0 = 4*(lane&31); head = lane&1.

__global__ __launch_bounds__(256) void k_agg1f(
    const int* __restrict__ row_start, const int4* __restrict__ csr,
    const _Float16* __restrict__ h1p, const float* __restrict__ b1p,
    const float* __restrict__ w2tp,
    const float* __restrict__ att_src2, const float* __restrict__ att_dst2,
    float* __restrict__ h2, float* __restrict__ as2, float* __restrict__ ad2) {
    __shared__ float w2l[16 * 136];     // permuted W2^T
    __shared__ float rows[4][128];      // permuted post-ELU rows
    int t = threadIdx.x;
    for (int i = t; i < 544; i += 256) ((float4*)w2l)[i] = ((const float4*)w2tp)[i];
    __syncthreads();
    int wv = t >> 6, lane = t & 63;
    int d = blockIdx.x * 4 + wv;
    int row = row_start[d], end = row_start[d + 1];
    int half = lane >> 5;
    int L = lane & 31;
    int c0 = L * 4;            // permuted channels
    int head = L & 1;          // perm: cperm%8>=4 <=> real c>=64 <=> L odd
    float den = 0.f;
    float4 acc = make_float4(0.f, 0.f, 0.f, 0.f);
    int i = row;
    for (; i + 8 <= end; i += 8) {
#pragma unroll
        for (int p = 0; p < 4; ++p) {
            int idx = i + 2 * p + half;
            int4 e4 = csr[idx];
            int s = e4.x;
            float we = head ? __int_as_float(e4.z) : __int_as_float(e4.y);
            uint2 u = *(const uint2*)(h1p + (size_t)s * 128 + c0);
            __half2 p0 = *(__half2*)&u.x;
            __half2 p1 = *(__half2*)&u.y;
            float2 f0 = __half22float2(p0);
            float2 f1 = __half22float2(p1);
            den += we;
            acc.x += we * f0.x; acc.y += we * f0.y;
            acc.z += we * f1.x; acc.w += we * f1.y;
        }
    }
    for (; i < end; i += 2) {
        int idx = i + half;
        bool ok = idx < end;
        int idxc = ok ? idx : i;
        int4 e4 = csr[idxc];
        int s = e4.x;
        float we = head ? __int_as_float(e4.z) : __int_as_float(e4.y);
        if (!ok) we = 0.f;
        uint2 u = *(const uint2*)(h1p + (size_t)s * 128 + c0);
        __half2 p0 = *(__half2*)&u.x;
        __half2 p1 = *(__half2*)&u.y;
        float2 f0 = __half22float2(p0);
        float2 f1 = __half22float2(p1);
        den += we;
        acc.x += we * f0.x; acc.y += we * f0.y;
        acc.z += we * f1.x; acc.w += we * f1.y;
    }
    den += __shfl_xor(den, 32, 64);
    acc.x += __shfl_xor(acc.x, 32, 64);
    acc.y += __shfl_xor(acc.y, 32, 64);
    acc.z += __shfl_xor(acc.z, 32, 64);
    acc.w += __shfl_xor(acc.w, 32, 64);
    float inv = 1.f / (den + GAT_EPS);
    float4 bv = ((const float4*)b1p)[L];
    float o0 = acc.x * inv + bv.x;
    float o1 = acc.y * inv + bv.y;
    float o2 = acc.z * inv + bv.z;
    float o3 = acc.w * inv + bv.w;
    o0 = (o0 > 0.f) ? o0 : expm1f(o0);   // ELU
    o1 = (o1 > 0.f) ? o1 : expm1f(o1);
    o2 = (o2 > 0.f) ? o2 : expm1f(o2);
    o3 = (o3 > 0.f) ? o3 : expm1f(o3);
    if (half == 0) *(float4*)(&rows[wv][c0]) = make_float4(o0, o1, o2, o3);
    // fused gemm2 (perm-consistent: rows and w2l share the permutation)
    int j = lane & 15, q = lane >> 4;
    const float* r = rows[wv];
    const float* wt = &w2l[j * 136];
    int k0 = q * 32;
    float acc2 = 0.f;
#pragma unroll
    for (int kk = 0; kk < 32; kk += 4) {
        float4 rv = *(const float4*)(r + k0 + kk);
        float4 w4 = *(const float4*)(wt + k0 + kk);
        acc2 += rv.x * w4.x + rv.y * w4.y + rv.z * w4.z + rv.w * w4.w;
    }
    acc2 += __shfl_xor(acc2, 16, 64);
    acc2 += __shfl_xor(acc2, 32, 64);
    if (lane < 16) {
        h2[(size_t)d * 16 + j] = acc2;
        float ps = acc2 * att_src2[j];
        float pd = acc2 * att_dst2[j];
#pragma unroll
        for (int off = 8; off >= 1; off >>= 1) {
            ps += __shfl_xor(ps, off, 64);
            pd += __shfl_xor(pd, off, 64);
        }
        if (lane == 0) { as2[d] = ps; ad2[d] = pd; }
    }
}

// ---------------- Layer 2 aggregation + bias + softmax: one wave per node ----------------

__global__ __launch_bounds__(256) void k_agg2(
    const int* __restrict__ row_start, const int4* __restrict__ csr,
    const float* __restrict__ h2, const float* __restrict__ as2,
    const float* __restrict__ ad2, const float* __restrict__ b2,
    float* __restrict__ out) {
    int t = threadIdx.x;
    int wv = t >> 6, lane = t & 63;
    int d = blockIdx.x * 4 + wv;
    int row = row_start[d], end = row_start[d + 1];
    float ad = ad2[d];
    int c = lane & 15, q = lane >> 4;
    float den = 0.f, acc = 0.f;
    for (int base = row; base < end; base += 64) {
        int idx = base + lane;
        float w = 0.f; int s = 0;
        if (idx < end) {
            s = csr[idx].x;
            float e = as2[s] + ad;
            e = (e >= 0.f) ? e : NEG_SLOPE * e;
            w = expf(e);
        }
        den += w;
        int m = end - base; if (m > 64) m = 64;
        for (int jj = 0; jj < m; jj += 4) {
            float wj = __shfl(w, jj + q, 64);
            int sj = __shfl(s, jj + q, 64);
            acc += wj * h2[(size_t)sj * 16 + c];
        }
    }
#pragma unroll
    for (int off = 32; off >= 1; off >>= 1) den += __shfl_xor(den, off, 64);
    acc += __shfl_xor(acc, 16, 64);
    acc += __shfl_xor(acc, 32, 64);
    float v = acc / (den + GAT_EPS) + b2[c];
    float mmax = v;
#pragma unroll
    for (int off = 8; off >= 1; off >>= 1) mmax = fmaxf(mmax, __shfl_xor(mmax, off, 16));
    float ex = expf(v - mmax);
    float sum = ex;
#pragma unroll
    for (int off = 8; off >= 1; off >>= 1) sum += __shfl_xor(sum, off, 16);
    if (lane < 16) out[(size_t)d * 16 + c] = ex / sum;
}

// ---------------- launch ----------------

extern "C" void kernel_launch(void* const* d_in, const int* in_sizes, int n_in,
                              void* d_out, int out_size, void* d_ws, size_t ws_size,
                              hipStream_t stream) {
    const float* x        = (const float*)d_in[0];
    const float* W1       = (const float*)d_in[1];
    const float* att_src1 = (const float*)d_in[2];
    const float* att_dst1 = (const float*)d_in[3];
    const float* b1       = (const float*)d_in[4];
    const float* W2       = (const float*)d_in[5];
    const float* att_src2 = (const float*)d_in[6];
    const float* att_dst2 = (const float*)d_in[7];
    const float* b2       = (const float*)d_in[8];
    const int*   ei       = (const int*)d_in[9];   // [2, E]: src row then dst row

    char* p = (char*)d_ws;
    auto alloc = [&](size_t bytes) {
        char* r = p;
        p += (bytes + 255) & ~(size_t)255;
        return r;
    };
    _Float16* x16  = (_Float16*)alloc(sizeof(_Float16) * (size_t)50048 * 128);
    _Float16* h1p  = (_Float16*)alloc(sizeof(_Float16) * (size_t)N_NODES * 128);
    _Float16* w1t  = (_Float16*)alloc(sizeof(_Float16) * 128 * 136);
    float* w2tp    = (float*)alloc(sizeof(float) * 16 * 136);
    float* b1p     = (float*)alloc(sizeof(float) * 128);
    float* h2      = (float*)alloc(sizeof(float) * (size_t)N_NODES * 16);
    float* a_src   = (float*)alloc(sizeof(float) * N_NODES * 2);
    float* a_dst   = (float*)alloc(sizeof(float) * N_NODES * 2);
    float* as2     = (float*)alloc(sizeof(float) * N_NODES);
    float* ad2     = (float*)alloc(sizeof(float) * N_NODES);
    int* cnt       = (int*)alloc(sizeof(int) * N_NODES * 2);  // cnt | fill, one memset
    int* fill      = cnt + N_NODES;
    int* row_start = (int*)alloc(sizeof(int) * (N_NODES + 1));
    int4* csr      = (int4*)alloc(sizeof(int4) * (size_t)N_EDGES);

    (void)hipMemsetAsync(cnt, 0, sizeof(int) * N_NODES * 2, stream);
    k_prep<<<6256, 256, 0, stream>>>(x, W1, W2, b1, ei, x16, w1t, w2tp, b1p, cnt);
    k_scan<<<1, 1024, 0, stream>>>(cnt, row_start);
    k_gemm1m<<<782, 256, 0, stream>>>(x16, w1t, att_src1, att_dst1, h1p, a_src, a_dst);
    k_scatter_w<<<(N_EDGES + 255) / 256, 256, 0, stream>>>(ei, row_start, fill, csr, a_src, a_dst, 0, 25000);
    k_scatter_w<<<(N_EDGES + 255) / 256, 256, 0, stream>>>(ei, row_start, fill, csr, a_src, a_dst, 25000, 50000);
    k_agg1f<<<N_NODES / 4, 256, 0, stream>>>(row_start, csr, h1p, b1p, w2tp, att_src2, att_dst2, h2, as2, ad2);
    k_agg2<<<N_NODES / 4, 256, 0, stream>>>(row_start, csr, h2, as2, ad2, b2, (float*)d_out);
}

// Round 11
// 278.707 us; speedup vs baseline: 1.4326x; 1.3656x over previous
//
#include <hip/hip_runtime.h>
#include <hip/hip_fp16.h>
#include <cstdint>
#include <cstddef>

#define N_NODES 50000
#define N_EDGES 1600000
#define NEG_SLOPE 0.2f
#define GAT_EPS 1e-16f

#define NCHUNK 128
#define CE (N_EDGES / NCHUNK)   // 12500
#define NBKT 196                 // ceil(50000/256)

typedef _Float16 half8v __attribute__((ext_vector_type(8)));
typedef float f32x4 __attribute__((ext_vector_type(4)));

// Channel permutation for h1 storage (MFMA C-reg native order):
// real c = ct*16 + m  <->  cperm = m*8 + ct

// ---------------- tiny prep: W1^T fp16 (padded), W2^T/b1 permuted ----------------

__global__ __launch_bounds__(256) void k_prep_tiny(
    const float* __restrict__ W1, const float* __restrict__ W2,
    const float* __restrict__ b1,
    _Float16* __restrict__ w1t, float* __restrict__ w2tp, float* __restrict__ b1p) {
    int t = threadIdx.x, b = blockIdx.x;
    if (b < 8) {
        for (int i = t; i < 2048; i += 256) {
            int idx = b * 2048 + i;
            int c = idx >> 7, k = idx & 127;
            w1t[c * 136 + k] = (_Float16)W1[k * 128 + c];
        }
    } else {
        for (int i = t; i < 2176; i += 256) {
            int j = i >> 7, kp = i & 127;
            int real = (kp & 7) * 16 + (kp >> 3);
            w2tp[j * 136 + kp] = W2[real * 16 + j];
        }
        if (t < 128) {
            int real = (t & 7) * 16 + (t >> 3);
            b1p[t] = b1[real];
        }
    }
}

// ---------------- CSR build, atomic-free (LDS atomics only) ----------------

__global__ __launch_bounds__(256) void k_hist(const int* __restrict__ ei,
                                              int* __restrict__ coarse) {
    __shared__ int h[NBKT];
    int t = threadIdx.x, g = blockIdx.x;
    if (t < NBKT) h[t] = 0;
    __syncthreads();
    int e0 = g * CE;
    for (int e = e0 + t; e < e0 + CE; e += 256)
        atomicAdd(&h[ei[N_EDGES + e] >> 8], 1);
    __syncthreads();
    if (t < NBKT) coarse[t * NCHUNK + g] = h[t];
}

__global__ __launch_bounds__(1024) void k_cscan(const int* __restrict__ coarse,
                                                int* __restrict__ cbase,
                                                int* __restrict__ bb,
                                                int* __restrict__ row_start) {
    __shared__ int cl[NBKT * NCHUNK];   // 100 KB
    __shared__ int btot[NBKT];
    __shared__ int bbase[NBKT];
    int t = threadIdx.x;
    for (int i = t; i < NBKT * NCHUNK; i += 1024) cl[i] = coarse[i];
    __syncthreads();
    if (t < NBKT) {
        int s = 0;
        for (int g = 0; g < NCHUNK; ++g) s += cl[t * NCHUNK + g];
        btot[t] = s;
    }
    __syncthreads();
    if (t == 0) {
        int base = 0;
        for (int b = 0; b < NBKT; ++b) { bbase[b] = base; base += btot[b]; }
    }
    __syncthreads();
    if (t < NBKT) {
        int run = bbase[t];
        bb[t] = run;
        for (int g = 0; g < NCHUNK; ++g) {
            cbase[t * NCHUNK + g] = run;
            run += cl[t * NCHUNK + g];
        }
    }
    if (t == 0) { bb[NBKT] = N_EDGES; row_start[N_NODES] = N_EDGES; }
}

__global__ __launch_bounds__(256) void k_partition(const int* __restrict__ ei,
                                                   const int* __restrict__ cbase,
                                                   int2* __restrict__ part) {
    __shared__ int loc[NBKT];
    int t = threadIdx.x, g = blockIdx.x;
    if (t < NBKT) loc[t] = cbase[t * NCHUNK + g];
    __syncthreads();
    int e0 = g * CE;
    for (int e = e0 + t; e < e0 + CE; e += 256) {
        int s = ei[e], d = ei[N_EDGES + e];
        int slot = atomicAdd(&loc[d >> 8], 1);
        part[slot] = make_int2(s, d);
    }
}

// per-bucket local sort + row_start + packed csr {src,w0,w1,0} with weights
__global__ __launch_bounds__(256) void k_local(const int2* __restrict__ part,
                                               const int* __restrict__ bb,
                                               const float* __restrict__ a_src1,
                                               const float* __restrict__ a_dst1,
                                               int* __restrict__ row_start,
                                               int4* __restrict__ csr) {
    __shared__ int hist[256];
    __shared__ int fillv[256];
    __shared__ float2 adl[256];
    __shared__ int wtot[4];
    int t = threadIdx.x, b = blockIdx.x;
    int n0 = b << 8;
    int es = bb[b], ee = bb[b + 1];
    hist[t] = 0;
    if (n0 + t < N_NODES) adl[t] = ((const float2*)a_dst1)[n0 + t];
    __syncthreads();
    for (int e = es + t; e < ee; e += 256) atomicAdd(&hist[part[e].y - n0], 1);
    __syncthreads();
    int lane = t & 63, w = t >> 6;
    int v = hist[t], x = v;
#pragma unroll
    for (int off = 1; off < 64; off <<= 1) {
        int y = __shfl_up(x, off, 64);
        if (lane >= off) x += y;
    }
    if (lane == 63) wtot[w] = x;
    __syncthreads();
    int woff = 0;
    for (int i = 0; i < w; ++i) woff += wtot[i];
    int excl = woff + x - v;
    if (n0 + t < N_NODES) row_start[n0 + t] = es + excl;
    fillv[t] = excl;
    __syncthreads();
    for (int e = es + t; e < ee; e += 256) {
        int2 sd = part[e];
        int j = sd.y - n0;
        int slot = es + atomicAdd(&fillv[j], 1);
        float2 as = ((const float2*)a_src1)[sd.x];
        float2 ad = adl[j];
        float e0 = as.x + ad.x; e0 = (e0 >= 0.f) ? e0 : NEG_SLOPE * e0;
        float e1 = as.y + ad.y; e1 = (e1 >= 0.f) ? e1 : NEG_SLOPE * e1;
        csr[slot] = make_int4(sd.x, __float_as_int(expf(e0)), __float_as_int(expf(e1)), 0);
    }
}

// ---------------- Layer 1 GEMM via MFMA f16 (x converted in-register) ----------------

__global__ __launch_bounds__(256) void k_gemm1m(
    const float* __restrict__ x, const _Float16* __restrict__ w1t,
    const float* __restrict__ att_src, const float* __restrict__ att_dst,
    _Float16* __restrict__ h1p, float* __restrict__ a_src, float* __restrict__ a_dst) {
    __shared__ _Float16 wl[128 * 136];   // 34816 B
    int t = threadIdx.x;
    {
        const uint4* src = (const uint4*)w1t;
        uint4* dst = (uint4*)wl;
        for (int j = t; j < 2176; j += 256) dst[j] = src[j];
    }
    __syncthreads();
    int wv = t >> 6, lane = t & 63;
    int m = lane & 15, q = lane >> 4;
    int nb = blockIdx.x * 64 + wv * 16;
    int grow = nb + m;
    const float* xrow = x + (size_t)((grow < N_NODES) ? grow : (N_NODES - 1)) * 128;
    f32x4 acc[8];
#pragma unroll
    for (int ct = 0; ct < 8; ++ct) acc[ct] = (f32x4){0.f, 0.f, 0.f, 0.f};
#pragma unroll
    for (int kc = 0; kc < 4; ++kc) {
        float4 u0 = *(const float4*)(xrow + kc * 32 + q * 8);
        float4 u1 = *(const float4*)(xrow + kc * 32 + q * 8 + 4);
        half8v a;
        a[0] = (_Float16)u0.x; a[1] = (_Float16)u0.y;
        a[2] = (_Float16)u0.z; a[3] = (_Float16)u0.w;
        a[4] = (_Float16)u1.x; a[5] = (_Float16)u1.y;
        a[6] = (_Float16)u1.z; a[7] = (_Float16)u1.w;
#pragma unroll
        for (int ct = 0; ct < 8; ++ct) {
            half8v bf = *(const half8v*)(wl + (ct * 16 + m) * 136 + kc * 32 + q * 8);
            acc[ct] = __builtin_amdgcn_mfma_f32_16x16x32_f16(a, bf, acc[ct], 0, 0, 0);
        }
    }
    float att_s[8], att_d[8];
#pragma unroll
    for (int ct = 0; ct < 8; ++ct) {
        att_s[ct] = att_src[ct * 16 + m];
        att_d[ct] = att_dst[ct * 16 + m];
    }
#pragma unroll
    for (int r = 0; r < 4; ++r) {
        int gn = nb + q * 4 + r;
        half8v hv;
        float ps0 = 0.f, ps1 = 0.f, pd0 = 0.f, pd1 = 0.f;
#pragma unroll
        for (int ct = 0; ct < 8; ++ct) {
            float v = acc[ct][r];
            hv[ct] = (_Float16)v;
            if (ct < 4) { ps0 += v * att_s[ct]; pd0 += v * att_d[ct]; }
            else        { ps1 += v * att_s[ct]; pd1 += v * att_d[ct]; }
        }
#pragma unroll
        for (int off = 8; off >= 1; off >>= 1) {
            ps0 += __shfl_xor(ps0, off, 64);
            ps1 += __shfl_xor(ps1, off, 64);
            pd0 += __shfl_xor(pd0, off, 64);
            pd1 += __shfl_xor(pd1, off, 64);
        }
        if (gn < N_NODES) {
            *(half8v*)(h1p + (size_t)gn * 128 + m * 8) = hv;
            if (m == 0) {
                a_src[gn * 2 + 0] = ps0;
                a_src[gn * 2 + 1] = ps1;
                a_dst[gn * 2 + 0] = pd0;
                a_dst[gn * 2 + 1] = pd1;
            }
        }
    }
}

// ---------------- Layer 1 aggregation + ELU + fused layer-2 GEMM ----------------
// One wave per node, pair-scheme: lanes 0..31 even edges, 32..63 odd edges.
// Channels in PERMUTED space: c0 = 4*(lane&31); head = (lane&31)&1.

__global__ __launch_bounds__(256) void k_agg1f(
    const int* __restrict__ row_start, const int4* __restrict__ csr,
    const _Float16* __restrict__ h1p, const float* __restrict__ b1p,
    const float* __restrict__ w2tp,
    const float* __restrict__ att_src2, const float* __restrict__ att_dst2,
    float* __restrict__ h2, float* __restrict__ as2, float* __restrict__ ad2) {
    __shared__ float w2l[16 * 136];
    __shared__ float rows[4][128];
    int t = threadIdx.x;
    for (int i = t; i < 544; i += 256) ((float4*)w2l)[i] = ((const float4*)w2tp)[i];
    __syncthreads();
    int wv = t >> 6, lane = t & 63;
    int d = blockIdx.x * 4 + wv;
    int row = row_start[d], end = row_start[d + 1];
    int half = lane >> 5;
    int L = lane & 31;
    int c0 = L * 4;
    int head = L & 1;
    float den = 0.f;
    float4 acc = make_float4(0.f, 0.f, 0.f, 0.f);
    int i = row;
    for (; i + 8 <= end; i += 8) {
#pragma unroll
        for (int p = 0; p < 4; ++p) {
            int idx = i + 2 * p + half;
            int4 e4 = csr[idx];
            int s = e4.x;
            float we = head ? __int_as_float(e4.z) : __int_as_float(e4.y);
            uint2 u = *(const uint2*)(h1p + (size_t)s * 128 + c0);
            __half2 p0 = *(__half2*)&u.x;
            __half2 p1 = *(__half2*)&u.y;
            float2 f0 = __half22float2(p0);
            float2 f1 = __half22float2(p1);
            den += we;
            acc.x += we * f0.x; acc.y += we * f0.y;
            acc.z += we * f1.x; acc.w += we * f1.y;
        }
    }
    for (; i < end; i += 2) {
        int idx = i + half;
        bool ok = idx < end;
        int idxc = ok ? idx : i;
        int4 e4 = csr[idxc];
        int s = e4.x;
        float we = head ? __int_as_float(e4.z) : __int_as_float(e4.y);
        if (!ok) we = 0.f;
        uint2 u = *(const uint2*)(h1p + (size_t)s * 128 + c0);
        __half2 p0 = *(__half2*)&u.x;
        __half2 p1 = *(__half2*)&u.y;
        float2 f0 = __half22float2(p0);
        float2 f1 = __half22float2(p1);
        den += we;
        acc.x += we * f0.x; acc.y += we * f0.y;
        acc.z += we * f1.x; acc.w += we * f1.y;
    }
    den += __shfl_xor(den, 32, 64);
    acc.x += __shfl_xor(acc.x, 32, 64);
    acc.y += __shfl_xor(acc.y, 32, 64);
    acc.z += __shfl_xor(acc.z, 32, 64);
    acc.w += __shfl_xor(acc.w, 32, 64);
    float inv = 1.f / (den + GAT_EPS);
    float4 bv = ((const float4*)b1p)[L];
    float o0 = acc.x * inv + bv.x;
    float o1 = acc.y * inv + bv.y;
    float o2 = acc.z * inv + bv.z;
    float o3 = acc.w * inv + bv.w;
    o0 = (o0 > 0.f) ? o0 : expm1f(o0);
    o1 = (o1 > 0.f) ? o1 : expm1f(o1);
    o2 = (o2 > 0.f) ? o2 : expm1f(o2);
    o3 = (o3 > 0.f) ? o3 : expm1f(o3);
    if (half == 0) *(float4*)(&rows[wv][c0]) = make_float4(o0, o1, o2, o3);
    int j = lane & 15, q = lane >> 4;
    const float* r = rows[wv];
    const float* wt = &w2l[j * 136];
    int k0 = q * 32;
    float acc2 = 0.f;
#pragma unroll
    for (int kk = 0; kk < 32; kk += 4) {
        float4 rv = *(const float4*)(r + k0 + kk);
        float4 w4 = *(const float4*)(wt + k0 + kk);
        acc2 += rv.x * w4.x + rv.y * w4.y + rv.z * w4.z + rv.w * w4.w;
    }
    acc2 += __shfl_xor(acc2, 16, 64);
    acc2 += __shfl_xor(acc2, 32, 64);
    if (lane < 16) {
        h2[(size_t)d * 16 + j] = acc2;
        float ps = acc2 * att_src2[j];
        float pd = acc2 * att_dst2[j];
#pragma unroll
        for (int off = 8; off >= 1; off >>= 1) {
            ps += __shfl_xor(ps, off, 64);
            pd += __shfl_xor(pd, off, 64);
        }
        if (lane == 0) { as2[d] = ps; ad2[d] = pd; }
    }
}

// ---------------- Layer 2 aggregation + bias + softmax: one wave per node ----------------

__global__ __launch_bounds__(256) void k_agg2(
    const int* __restrict__ row_start, const int4* __restrict__ csr,
    const float* __restrict__ h2, const float* __restrict__ as2,
    const float* __restrict__ ad2, const float* __restrict__ b2,
    float* __restrict__ out) {
    int t = threadIdx.x;
    int wv = t >> 6, lane = t & 63;
    int d = blockIdx.x * 4 + wv;
    int row = row_start[d], end = row_start[d + 1];
    float ad = ad2[d];
    int c = lane & 15, q = lane >> 4;
    float den = 0.f, acc = 0.f;
    for (int base = row; base < end; base += 64) {
        int idx = base + lane;
        float w = 0.f; int s = 0;
        if (idx < end) {
            s = csr[idx].x;
            float e = as2[s] + ad;
            e = (e >= 0.f) ? e : NEG_SLOPE * e;
            w = expf(e);
        }
        den += w;
        int m = end - base; if (m > 64) m = 64;
        for (int jj = 0; jj < m; jj += 4) {
            float wj = __shfl(w, jj + q, 64);
            int sj = __shfl(s, jj + q, 64);
            acc += wj * h2[(size_t)sj * 16 + c];
        }
    }
#pragma unroll
    for (int off = 32; off >= 1; off >>= 1) den += __shfl_xor(den, off, 64);
    acc += __shfl_xor(acc, 16, 64);
    acc += __shfl_xor(acc, 32, 64);
    float v = acc / (den + GAT_EPS) + b2[c];
    float mmax = v;
#pragma unroll
    for (int off = 8; off >= 1; off >>= 1) mmax = fmaxf(mmax, __shfl_xor(mmax, off, 16));
    float ex = expf(v - mmax);
    float sum = ex;
#pragma unroll
    for (int off = 8; off >= 1; off >>= 1) sum += __shfl_xor(sum, off, 16);
    if (lane < 16) out[(size_t)d * 16 + c] = ex / sum;
}

// ---------------- launch ----------------

extern "C" void kernel_launch(void* const* d_in, const int* in_sizes, int n_in,
                              void* d_out, int out_size, void* d_ws, size_t ws_size,
                              hipStream_t stream) {
    const float* x        = (const float*)d_in[0];
    const float* W1       = (const float*)d_in[1];
    const float* att_src1 = (const float*)d_in[2];
    const float* att_dst1 = (const float*)d_in[3];
    const float* b1       = (const float*)d_in[4];
    const float* W2       = (const float*)d_in[5];
    const float* att_src2 = (const float*)d_in[6];
    const float* att_dst2 = (const float*)d_in[7];
    const float* b2       = (const float*)d_in[8];
    const int*   ei       = (const int*)d_in[9];   // [2, E]: src row then dst row

    char* p = (char*)d_ws;
    auto alloc = [&](size_t bytes) {
        char* r = p;
        p += (bytes + 255) & ~(size_t)255;
        return r;
    };
    _Float16* h1p  = (_Float16*)alloc(sizeof(_Float16) * (size_t)N_NODES * 128);
    _Float16* w1t  = (_Float16*)alloc(sizeof(_Float16) * 128 * 136);
    float* w2tp    = (float*)alloc(sizeof(float) * 16 * 136);
    float* b1p     = (float*)alloc(sizeof(float) * 128);
    float* h2      = (float*)alloc(sizeof(float) * (size_t)N_NODES * 16);
    float* a_src   = (float*)alloc(sizeof(float) * N_NODES * 2);
    float* a_dst   = (float*)alloc(sizeof(float) * N_NODES * 2);
    float* as2     = (float*)alloc(sizeof(float) * N_NODES);
    float* ad2     = (float*)alloc(sizeof(float) * N_NODES);
    int* coarse    = (int*)alloc(sizeof(int) * NBKT * NCHUNK);
    int* cbase     = (int*)alloc(sizeof(int) * NBKT * NCHUNK);
    int* bb        = (int*)alloc(sizeof(int) * (NBKT + 1));
    int* row_start = (int*)alloc(sizeof(int) * (N_NODES + 1));
    int2* part     = (int2*)alloc(sizeof(int2) * (size_t)N_EDGES);
    int4* csr      = (int4*)alloc(sizeof(int4) * (size_t)N_EDGES);

    k_prep_tiny<<<9, 256, 0, stream>>>(W1, W2, b1, w1t, w2tp, b1p);
    k_gemm1m<<<782, 256, 0, stream>>>(x, w1t, att_src1, att_dst1, h1p, a_src, a_dst);
    k_hist<<<NCHUNK, 256, 0, stream>>>(ei, coarse);
    k_cscan<<<1, 1024, 0, stream>>>(coarse, cbase, bb, row_start);
    k_partition<<<NCHUNK, 256, 0, stream>>>(ei, cbase, part);
    k_local<<<NBKT, 256, 0, stream>>>(part, bb, a_src, a_dst, row_start, csr);
    k_agg1f<<<N_NODES / 4, 256, 0, stream>>>(row_start, csr, h1p, b1p, w2tp, att_src2, att_dst2, h2, as2, ad2);
    k_agg2<<<N_NODES / 4, 256, 0, stream>>>(row_start, csr, h2, as2, ad2, b2, (float*)d_out);
}

// Round 12
// 267.200 us; speedup vs baseline: 1.4943x; 1.0431x over previous
//
#include <hip/hip_runtime.h>
#include <hip/hip_fp16.h>
#include <cstdint>
#include <cstddef>

#define N_NODES 50000
#define N_EDGES 1600000
#define NEG_SLOPE 0.2f
#define GAT_EPS 1e-16f

#define NCHUNK 128
#define CE (N_EDGES / NCHUNK)   // 12500
#define NBKT 196                 // ceil(50000/256)
#define GEMM_BLOCKS 782          // ceil(50000/64)

typedef _Float16 half8v __attribute__((ext_vector_type(8)));
typedef float f32x4 __attribute__((ext_vector_type(4)));

// Channel permutation for h1 storage (MFMA C-reg native order):
// real c = ct*16 + m  <->  cperm = m*8 + ct

// ---------------- tiny prep: W1^T fp16 (padded), W2^T/b1 permuted ----------------

__global__ __launch_bounds__(256) void k_prep_tiny(
    const float* __restrict__ W1, const float* __restrict__ W2,
    const float* __restrict__ b1,
    _Float16* __restrict__ w1t, float* __restrict__ w2tp, float* __restrict__ b1p) {
    int t = threadIdx.x, b = blockIdx.x;
    if (b < 8) {
        for (int i = t; i < 2048; i += 256) {
            int idx = b * 2048 + i;
            int c = idx >> 7, k = idx & 127;
            w1t[c * 136 + k] = (_Float16)W1[k * 128 + c];
        }
    } else {
        for (int i = t; i < 2112; i += 256) {   // 16 x 132
            int j = i / 132, kp = i % 132;
            if (kp < 128) {
                int real = (kp & 7) * 16 + (kp >> 3);
                w2tp[j * 132 + kp] = W2[real * 16 + j];
            } else {
                w2tp[j * 132 + kp] = 0.f;
            }
        }
        if (t < 128) {
            int real = (t & 7) * 16 + (t >> 3);
            b1p[t] = b1[real];
        }
    }
}

// ---------------- fused: Layer-1 MFMA GEMM blocks + coarse-histogram blocks ----------------

__global__ __launch_bounds__(256) void k_gh(
    const float* __restrict__ x, const _Float16* __restrict__ w1t,
    const float* __restrict__ att_src, const float* __restrict__ att_dst,
    _Float16* __restrict__ h1p, float* __restrict__ a_src, float* __restrict__ a_dst,
    const int* __restrict__ ei, int* __restrict__ coarse) {
    __shared__ __align__(16) char smem[34816];
    int t = threadIdx.x;
    int b = blockIdx.x;
    if (b >= GEMM_BLOCKS) {
        // ---- histogram branch ----
        int* h = (int*)smem;
        int g = b - GEMM_BLOCKS;
        if (t < NBKT) h[t] = 0;
        __syncthreads();
        int e0 = g * CE;
        for (int e = e0 + t; e < e0 + CE; e += 256)
            atomicAdd(&h[ei[N_EDGES + e] >> 8], 1);
        __syncthreads();
        if (t < NBKT) coarse[t * NCHUNK + g] = h[t];
        return;
    }
    // ---- MFMA GEMM branch ----
    _Float16* wl = (_Float16*)smem;      // [128][136]
    {
        const uint4* src = (const uint4*)w1t;
        uint4* dst = (uint4*)wl;
        for (int j = t; j < 2176; j += 256) dst[j] = src[j];
    }
    __syncthreads();
    int wv = t >> 6, lane = t & 63;
    int m = lane & 15, q = lane >> 4;
    int nb = b * 64 + wv * 16;
    int grow = nb + m;
    const float* xrow = x + (size_t)((grow < N_NODES) ? grow : (N_NODES - 1)) * 128;
    f32x4 acc[8];
#pragma unroll
    for (int ct = 0; ct < 8; ++ct) acc[ct] = (f32x4){0.f, 0.f, 0.f, 0.f};
#pragma unroll
    for (int kc = 0; kc < 4; ++kc) {
        float4 u0 = *(const float4*)(xrow + kc * 32 + q * 8);
        float4 u1 = *(const float4*)(xrow + kc * 32 + q * 8 + 4);
        half8v a;
        a[0] = (_Float16)u0.x; a[1] = (_Float16)u0.y;
        a[2] = (_Float16)u0.z; a[3] = (_Float16)u0.w;
        a[4] = (_Float16)u1.x; a[5] = (_Float16)u1.y;
        a[6] = (_Float16)u1.z; a[7] = (_Float16)u1.w;
#pragma unroll
        for (int ct = 0; ct < 8; ++ct) {
            half8v bf = *(const half8v*)(wl + (ct * 16 + m) * 136 + kc * 32 + q * 8);
            acc[ct] = __builtin_amdgcn_mfma_f32_16x16x32_f16(a, bf, acc[ct], 0, 0, 0);
        }
    }
    float att_s[8], att_d[8];
#pragma unroll
    for (int ct = 0; ct < 8; ++ct) {
        att_s[ct] = att_src[ct * 16 + m];
        att_d[ct] = att_dst[ct * 16 + m];
    }
#pragma unroll
    for (int r = 0; r < 4; ++r) {
        int gn = nb + q * 4 + r;
        half8v hv;
        float ps0 = 0.f, ps1 = 0.f, pd0 = 0.f, pd1 = 0.f;
#pragma unroll
        for (int ct = 0; ct < 8; ++ct) {
            float v = acc[ct][r];
            hv[ct] = (_Float16)v;
            if (ct < 4) { ps0 += v * att_s[ct]; pd0 += v * att_d[ct]; }
            else        { ps1 += v * att_s[ct]; pd1 += v * att_d[ct]; }
        }
#pragma unroll
        for (int off = 8; off >= 1; off >>= 1) {
            ps0 += __shfl_xor(ps0, off, 64);
            ps1 += __shfl_xor(ps1, off, 64);
            pd0 += __shfl_xor(pd0, off, 64);
            pd1 += __shfl_xor(pd1, off, 64);
        }
        if (gn < N_NODES) {
            *(half8v*)(h1p + (size_t)gn * 128 + m * 8) = hv;
            if (m == 0) {
                a_src[gn * 2 + 0] = ps0;
                a_src[gn * 2 + 1] = ps1;
                a_dst[gn * 2 + 0] = pd0;
                a_dst[gn * 2 + 1] = pd1;
            }
        }
    }
}

// ---------------- CSR build (LDS atomics only) ----------------

__global__ __launch_bounds__(1024) void k_cscan(const int* __restrict__ coarse,
                                                int* __restrict__ cbase,
                                                int* __restrict__ bb,
                                                int* __restrict__ row_start) {
    __shared__ int cl[NBKT * NCHUNK];   // 100 KB
    __shared__ int btot[NBKT];
    __shared__ int bbase[NBKT];
    int t = threadIdx.x;
    for (int i = t; i < NBKT * NCHUNK; i += 1024) cl[i] = coarse[i];
    __syncthreads();
    if (t < NBKT) {
        int s = 0;
        for (int g = 0; g < NCHUNK; ++g) s += cl[t * NCHUNK + g];
        btot[t] = s;
    }
    __syncthreads();
    if (t == 0) {
        int base = 0;
        for (int b = 0; b < NBKT; ++b) { bbase[b] = base; base += btot[b]; }
    }
    __syncthreads();
    if (t < NBKT) {
        int run = bbase[t];
        bb[t] = run;
        for (int g = 0; g < NCHUNK; ++g) {
            cbase[t * NCHUNK + g] = run;
            run += cl[t * NCHUNK + g];
        }
    }
    if (t == 0) { bb[NBKT] = N_EDGES; row_start[N_NODES] = N_EDGES; }
}

__global__ __launch_bounds__(256) void k_partition(const int* __restrict__ ei,
                                                   const int* __restrict__ cbase,
                                                   int2* __restrict__ part) {
    __shared__ int loc[NBKT];
    int t = threadIdx.x, g = blockIdx.x;
    if (t < NBKT) loc[t] = cbase[t * NCHUNK + g];
    __syncthreads();
    int e0 = g * CE;
    for (int e = e0 + t; e < e0 + CE; e += 256) {
        int s = ei[e], d = ei[N_EDGES + e];
        int slot = atomicAdd(&loc[d >> 8], 1);
        part[slot] = make_int2(s, d);
    }
}

__global__ __launch_bounds__(256) void k_local(const int2* __restrict__ part,
                                               const int* __restrict__ bb,
                                               const float* __restrict__ a_src1,
                                               const float* __restrict__ a_dst1,
                                               int* __restrict__ row_start,
                                               int4* __restrict__ csr) {
    __shared__ int hist[256];
    __shared__ int fillv[256];
    __shared__ float2 adl[256];
    __shared__ int wtot[4];
    int t = threadIdx.x, b = blockIdx.x;
    int n0 = b << 8;
    int es = bb[b], ee = bb[b + 1];
    hist[t] = 0;
    if (n0 + t < N_NODES) adl[t] = ((const float2*)a_dst1)[n0 + t];
    __syncthreads();
    for (int e = es + t; e < ee; e += 256) atomicAdd(&hist[part[e].y - n0], 1);
    __syncthreads();
    int lane = t & 63, w = t >> 6;
    int v = hist[t], x = v;
#pragma unroll
    for (int off = 1; off < 64; off <<= 1) {
        int y = __shfl_up(x, off, 64);
        if (lane >= off) x += y;
    }
    if (lane == 63) wtot[w] = x;
    __syncthreads();
    int woff = 0;
    for (int i = 0; i < w; ++i) woff += wtot[i];
    int excl = woff + x - v;
    if (n0 + t < N_NODES) row_start[n0 + t] = es + excl;
    fillv[t] = excl;
    __syncthreads();
    for (int e = es + t; e < ee; e += 256) {
        int2 sd = part[e];
        int j = sd.y - n0;
        int slot = es + atomicAdd(&fillv[j], 1);
        float2 as = ((const float2*)a_src1)[sd.x];
        float2 ad = adl[j];
        float e0 = as.x + ad.x; e0 = (e0 >= 0.f) ? e0 : NEG_SLOPE * e0;
        float e1 = as.y + ad.y; e1 = (e1 >= 0.f) ? e1 : NEG_SLOPE * e1;
        csr[slot] = make_int4(sd.x, __float_as_int(expf(e0)), __float_as_int(expf(e1)), 0);
    }
}

// ---------------- Layer 1 aggregation + ELU + fused layer-2 GEMM ----------------
// One wave per node, pair-scheme halves; channels in PERMUTED space.
// LDS: w2l stride 132 (2-way-only aliasing); fused-gemm2 reads use q-rotated
// phase so the 4 q-groups hit disjoint bank quadruples.

__global__ __launch_bounds__(256) void k_agg1f(
    const int* __restrict__ row_start, const int4* __restrict__ csr,
    const _Float16* __restrict__ h1p, const float* __restrict__ b1p,
    const float* __restrict__ w2tp,
    const float* __restrict__ att_src2, const float* __restrict__ att_dst2,
    float* __restrict__ h2, float* __restrict__ as2, float* __restrict__ ad2) {
    __shared__ float w2l[16 * 132];
    __shared__ float rows[4][128];
    int t = threadIdx.x;
    for (int i = t; i < 528; i += 256) ((float4*)w2l)[i] = ((const float4*)w2tp)[i];
    __syncthreads();
    int wv = t >> 6, lane = t & 63;
    int d = blockIdx.x * 4 + wv;
    int row = row_start[d], end = row_start[d + 1];
    int half = lane >> 5;
    int L = lane & 31;
    int c0 = L * 4;
    int head = L & 1;
    float den = 0.f;
    float4 acc = make_float4(0.f, 0.f, 0.f, 0.f);
    int i = row;
    for (; i + 8 <= end; i += 8) {
#pragma unroll
        for (int p = 0; p < 4; ++p) {
            int idx = i + 2 * p + half;
            int4 e4 = csr[idx];
            int s = e4.x;
            float we = head ? __int_as_float(e4.z) : __int_as_float(e4.y);
            uint2 u = *(const uint2*)(h1p + (size_t)s * 128 + c0);
            __half2 p0 = *(__half2*)&u.x;
            __half2 p1 = *(__half2*)&u.y;
            float2 f0 = __half22float2(p0);
            float2 f1 = __half22float2(p1);
            den += we;
            acc.x += we * f0.x; acc.y += we * f0.y;
            acc.z += we * f1.x; acc.w += we * f1.y;
        }
    }
    for (; i < end; i += 2) {
        int idx = i + half;
        bool ok = idx < end;
        int idxc = ok ? idx : i;
        int4 e4 = csr[idxc];
        int s = e4.x;
        float we = head ? __int_as_float(e4.z) : __int_as_float(e4.y);
        if (!ok) we = 0.f;
        uint2 u = *(const uint2*)(h1p + (size_t)s * 128 + c0);
        __half2 p0 = *(__half2*)&u.x;
        __half2 p1 = *(__half2*)&u.y;
        float2 f0 = __half22float2(p0);
        float2 f1 = __half22float2(p1);
        den += we;
        acc.x += we * f0.x; acc.y += we * f0.y;
        acc.z += we * f1.x; acc.w += we * f1.y;
    }
    den += __shfl_xor(den, 32, 64);
    acc.x += __shfl_xor(acc.x, 32, 64);
    acc.y += __shfl_xor(acc.y, 32, 64);
    acc.z += __shfl_xor(acc.z, 32, 64);
    acc.w += __shfl_xor(acc.w, 32, 64);
    float inv = 1.f / (den + GAT_EPS);
    float4 bv = ((const float4*)b1p)[L];
    float o0 = acc.x * inv + bv.x;
    float o1 = acc.y * inv + bv.y;
    float o2 = acc.z * inv + bv.z;
    float o3 = acc.w * inv + bv.w;
    o0 = (o0 > 0.f) ? o0 : expm1f(o0);
    o1 = (o1 > 0.f) ? o1 : expm1f(o1);
    o2 = (o2 > 0.f) ? o2 : expm1f(o2);
    o3 = (o3 > 0.f) ? o3 : expm1f(o3);
    if (half == 0) *(float4*)(&rows[wv][c0]) = make_float4(o0, o1, o2, o3);
    // fused gemm2, q-rotated phases
    int j = lane & 15, q = lane >> 4;
    const float* r = rows[wv];
    const float* wt = &w2l[j * 132];
    int k0 = q * 32;
    float acc2 = 0.f;
#pragma unroll
    for (int sI = 0; sI < 8; ++sI) {
        int sp = ((sI + q) & 7) * 4;
        float4 rv = *(const float4*)(r + k0 + sp);
        float4 w4 = *(const float4*)(wt + k0 + sp);
        acc2 += rv.x * w4.x + rv.y * w4.y + rv.z * w4.z + rv.w * w4.w;
    }
    acc2 += __shfl_xor(acc2, 16, 64);
    acc2 += __shfl_xor(acc2, 32, 64);
    if (lane < 16) {
        h2[(size_t)d * 16 + j] = acc2;
        float ps = acc2 * att_src2[j];
        float pd = acc2 * att_dst2[j];
#pragma unroll
        for (int off = 8; off >= 1; off >>= 1) {
            ps += __shfl_xor(ps, off, 64);
            pd += __shfl_xor(pd, off, 64);
        }
        if (lane == 0) { as2[d] = ps; ad2[d] = pd; }
    }
}

// ---------------- Layer 2 aggregation + bias + softmax: one wave per node ----------------

__global__ __launch_bounds__(256) void k_agg2(
    const int* __restrict__ row_start, const int4* __restrict__ csr,
    const float* __restrict__ h2, const float* __restrict__ as2,
    const float* __restrict__ ad2, const float* __restrict__ b2,
    float* __restrict__ out) {
    int t = threadIdx.x;
    int wv = t >> 6, lane = t & 63;
    int d = blockIdx.x * 4 + wv;
    int row = row_start[d], end = row_start[d + 1];
    float ad = ad2[d];
    int c = lane & 15, q = lane >> 4;
    float den = 0.f, acc = 0.f;
    for (int base = row; base < end; base += 64) {
        int idx = base + lane;
        float w = 0.f; int s = 0;
        if (idx < end) {
            s = csr[idx].x;
            float e = as2[s] + ad;
            e = (e >= 0.f) ? e : NEG_SLOPE * e;
            w = expf(e);
        }
        den += w;
        int m = end - base; if (m > 64) m = 64;
        int jj = 0;
        for (; jj + 8 <= m; jj += 8) {
            float w0 = __shfl(w, jj + q, 64);
            int   s0 = __shfl(s, jj + q, 64);
            float w1_ = __shfl(w, jj + 4 + q, 64);
            int   s1 = __shfl(s, jj + 4 + q, 64);
            float h0 = h2[(size_t)s0 * 16 + c];
            float h1_ = h2[(size_t)s1 * 16 + c];
            acc += w0 * h0 + w1_ * h1_;
        }
        for (; jj < m; jj += 4) {
            float wj = __shfl(w, jj + q, 64);
            int sj = __shfl(s, jj + q, 64);
            acc += wj * h2[(size_t)sj * 16 + c];
        }
    }
#pragma unroll
    for (int off = 32; off >= 1; off >>= 1) den += __shfl_xor(den, off, 64);
    acc += __shfl_xor(acc, 16, 64);
    acc += __shfl_xor(acc, 32, 64);
    float v = acc / (den + GAT_EPS) + b2[c];
    float mmax = v;
#pragma unroll
    for (int off = 8; off >= 1; off >>= 1) mmax = fmaxf(mmax, __shfl_xor(mmax, off, 16));
    float ex = expf(v - mmax);
    float sum = ex;
#pragma unroll
    for (int off = 8; off >= 1; off >>= 1) sum += __shfl_xor(sum, off, 16);
    if (lane < 16) out[(size_t)d * 16 + c] = ex / sum;
}

// ---------------- launch ----------------

extern "C" void kernel_launch(void* const* d_in, const int* in_sizes, int n_in,
                              void* d_out, int out_size, void* d_ws, size_t ws_size,
                              hipStream_t stream) {
    const float* x        = (const float*)d_in[0];
    const float* W1       = (const float*)d_in[1];
    const float* att_src1 = (const float*)d_in[2];
    const float* att_dst1 = (const float*)d_in[3];
    const float* b1       = (const float*)d_in[4];
    const float* W2       = (const float*)d_in[5];
    const float* att_src2 = (const float*)d_in[6];
    const float* att_dst2 = (const float*)d_in[7];
    const float* b2       = (const float*)d_in[8];
    const int*   ei       = (const int*)d_in[9];   // [2, E]: src row then dst row

    char* p = (char*)d_ws;
    auto alloc = [&](size_t bytes) {
        char* r = p;
        p += (bytes + 255) & ~(size_t)255;
        return r;
    };
    _Float16* h1p  = (_Float16*)alloc(sizeof(_Float16) * (size_t)N_NODES * 128);
    _Float16* w1t  = (_Float16*)alloc(sizeof(_Float16) * 128 * 136);
    float* w2tp    = (float*)alloc(sizeof(float) * 16 * 132);
    float* b1p     = (float*)alloc(sizeof(float) * 128);
    float* h2      = (float*)alloc(sizeof(float) * (size_t)N_NODES * 16);
    float* a_src   = (float*)alloc(sizeof(float) * N_NODES * 2);
    float* a_dst   = (float*)alloc(sizeof(float) * N_NODES * 2);
    float* as2     = (float*)alloc(sizeof(float) * N_NODES);
    float* ad2     = (float*)alloc(sizeof(float) * N_NODES);
    int* coarse    = (int*)alloc(sizeof(int) * NBKT * NCHUNK);
    int* cbase     = (int*)alloc(sizeof(int) * NBKT * NCHUNK);
    int* bb        = (int*)alloc(sizeof(int) * (NBKT + 1));
    int* row_start = (int*)alloc(sizeof(int) * (N_NODES + 1));
    int2* part     = (int2*)alloc(sizeof(int2) * (size_t)N_EDGES);
    int4* csr      = (int4*)alloc(sizeof(int4) * (size_t)N_EDGES);

    k_prep_tiny<<<9, 256, 0, stream>>>(W1, W2, b1, w1t, w2tp, b1p);
    k_gh<<<GEMM_BLOCKS + NCHUNK, 256, 0, stream>>>(x, w1t, att_src1, att_dst1, h1p, a_src, a_dst, ei, coarse);
    k_cscan<<<1, 1024, 0, stream>>>(coarse, cbase, bb, row_start);
    k_partition<<<NCHUNK, 256, 0, stream>>>(ei, cbase, part);
    k_local<<<NBKT, 256, 0, stream>>>(part, bb, a_src, a_dst, row_start, csr);
    k_agg1f<<<N_NODES / 4, 256, 0, stream>>>(row_start, csr, h1p, b1p, w2tp, att_src2, att_dst2, h2, as2, ad2);
    k_agg2<<<N_NODES / 4, 256, 0, stream>>>(row_start, csr, h2, as2, ad2, b2, (float*)d_out);
}